// Round 1
// baseline (519.454 us; speedup 1.0000x reference)
//
#include <hip/hip_runtime.h>
#include <cstdint>
#include <cstddef>

// Problem constants (from reference): x [8,4096,512] fp32, W_enc [512,512],
// b_enc [512], code_book [128,512]. Outputs: q (reshaped), q, z  -> 3 x B*DIM fp32.
#define DIM     512
#define NCODES  128
#define BM      128   // rows per block tile
#define BK      16    // K chunk
#define LDSPAD  4     // keeps 16B alignment of As[k][*] rows (132 floats = 528B, %16==0)

// ---------------------------------------------------------------------------
// Kernel 0: per-code squared norms -> ws (128 floats). Tiny.
// ---------------------------------------------------------------------------
__global__ void code_norms_kernel(const float* __restrict__ cb,
                                  float* __restrict__ cn) {
    int j = threadIdx.x;             // 128 threads, 1 block
    if (j < NCODES) {
        float s = 0.f;
        const float* row = cb + (size_t)j * DIM;
        #pragma unroll 8
        for (int k = 0; k < DIM; ++k) s = fmaf(row[k], row[k], s);
        cn[j] = s;
    }
}

// ---------------------------------------------------------------------------
// Kernel 1: Z[m][n] = sum_k X[m][k]*W[n][k] + bias[n]
// Both operands K-contiguous ("NT" gemm). 128x128 tile, 256 threads,
// 8x8 accumulators per thread, BK=16 LDS staging.
// ---------------------------------------------------------------------------
__global__ __launch_bounds__(256) void gemm_xwt_kernel(
        const float* __restrict__ X, const float* __restrict__ W,
        const float* __restrict__ bias, float* __restrict__ Z) {
    __shared__ float As[BK][BM + LDSPAD];   // [k][m]
    __shared__ float Bs[BK][BM + LDSPAD];   // [k][n]

    const int tid = threadIdx.x;
    const int tx = tid & 15;        // 0..15 -> 8 cols each
    const int ty = tid >> 4;        // 0..15 -> 8 rows each
    const size_t row0 = (size_t)blockIdx.x * BM;
    const size_t col0 = (size_t)blockIdx.y * BM;

    float acc[8][8] = {};

    for (int k0 = 0; k0 < DIM; k0 += BK) {
        // Stage: 128 rows x 16 k each for A and B = 512 float4 each; 2/thread.
        #pragma unroll
        for (int i = 0; i < 2; ++i) {
            int l  = tid * 2 + i;         // 0..511
            int r  = l >> 2;              // 0..127
            int kq = l & 3;               // float4 index within the 16-wide k chunk
            float4 va = *(const float4*)&X[(row0 + r) * DIM + k0 + kq * 4];
            As[kq * 4 + 0][r] = va.x; As[kq * 4 + 1][r] = va.y;
            As[kq * 4 + 2][r] = va.z; As[kq * 4 + 3][r] = va.w;
            float4 vb = *(const float4*)&W[(col0 + r) * DIM + k0 + kq * 4];
            Bs[kq * 4 + 0][r] = vb.x; Bs[kq * 4 + 1][r] = vb.y;
            Bs[kq * 4 + 2][r] = vb.z; Bs[kq * 4 + 3][r] = vb.w;
        }
        __syncthreads();

        #pragma unroll
        for (int k = 0; k < BK; ++k) {
            float4 a0 = *(const float4*)&As[k][ty * 8];
            float4 a1 = *(const float4*)&As[k][ty * 8 + 4];
            float4 b0 = *(const float4*)&Bs[k][tx * 8];
            float4 b1 = *(const float4*)&Bs[k][tx * 8 + 4];
            float a[8] = {a0.x, a0.y, a0.z, a0.w, a1.x, a1.y, a1.z, a1.w};
            float b[8] = {b0.x, b0.y, b0.z, b0.w, b1.x, b1.y, b1.z, b1.w};
            #pragma unroll
            for (int i = 0; i < 8; ++i)
                #pragma unroll
                for (int j = 0; j < 8; ++j)
                    acc[i][j] = fmaf(a[i], b[j], acc[i][j]);
        }
        __syncthreads();
    }

    // Epilogue: + bias, store 8x8 per thread as float4 pairs.
    #pragma unroll
    for (int i = 0; i < 8; ++i) {
        size_t r = row0 + ty * 8 + i;
        #pragma unroll
        for (int j = 0; j < 8; j += 4) {
            size_t c = col0 + tx * 8 + j;
            float4 v;
            v.x = acc[i][j + 0] + bias[c + 0];
            v.y = acc[i][j + 1] + bias[c + 1];
            v.z = acc[i][j + 2] + bias[c + 2];
            v.w = acc[i][j + 3] + bias[c + 3];
            *(float4*)&Z[r * DIM + c] = v;
        }
    }
}

// ---------------------------------------------------------------------------
// Kernel 2: per 128-row block: S = Z·CBᵀ (128x128, K=512), score = cn - 2S,
// row argmin (first-index tie-break, numpy semantics), gather codebook row to
// q1 and q2.
// ---------------------------------------------------------------------------
__global__ __launch_bounds__(256) void vq_argmin_gather_kernel(
        const float* __restrict__ Z, const float* __restrict__ cb,
        const float* __restrict__ cn, float* __restrict__ q1,
        float* __restrict__ q2) {
    __shared__ float Zs[BK][BM + LDSPAD];
    __shared__ float Cs[BK][NCODES + LDSPAD];
    __shared__ float cnS[NCODES];
    __shared__ float red_v[BM][17];
    __shared__ int   red_i[BM][17];
    __shared__ int   amin[BM];

    const int tid = threadIdx.x;
    const int tx = tid & 15;
    const int ty = tid >> 4;
    const size_t row0 = (size_t)blockIdx.x * BM;

    if (tid < NCODES) cnS[tid] = cn[tid];

    float acc[8][8] = {};

    for (int k0 = 0; k0 < DIM; k0 += BK) {
        #pragma unroll
        for (int i = 0; i < 2; ++i) {
            int l  = tid * 2 + i;
            int r  = l >> 2;
            int kq = l & 3;
            float4 vz = *(const float4*)&Z[(row0 + r) * DIM + k0 + kq * 4];
            Zs[kq * 4 + 0][r] = vz.x; Zs[kq * 4 + 1][r] = vz.y;
            Zs[kq * 4 + 2][r] = vz.z; Zs[kq * 4 + 3][r] = vz.w;
            float4 vc = *(const float4*)&cb[(size_t)r * DIM + k0 + kq * 4];
            Cs[kq * 4 + 0][r] = vc.x; Cs[kq * 4 + 1][r] = vc.y;
            Cs[kq * 4 + 2][r] = vc.z; Cs[kq * 4 + 3][r] = vc.w;
        }
        __syncthreads();

        #pragma unroll
        for (int k = 0; k < BK; ++k) {
            float4 a0 = *(const float4*)&Zs[k][ty * 8];
            float4 a1 = *(const float4*)&Zs[k][ty * 8 + 4];
            float4 b0 = *(const float4*)&Cs[k][tx * 8];
            float4 b1 = *(const float4*)&Cs[k][tx * 8 + 4];
            float a[8] = {a0.x, a0.y, a0.z, a0.w, a1.x, a1.y, a1.z, a1.w};
            float b[8] = {b0.x, b0.y, b0.z, b0.w, b1.x, b1.y, b1.z, b1.w};
            #pragma unroll
            for (int i = 0; i < 8; ++i)
                #pragma unroll
                for (int j = 0; j < 8; ++j)
                    acc[i][j] = fmaf(a[i], b[j], acc[i][j]);
        }
        __syncthreads();
    }

    // Per-thread argmin over its 8 codes (ascending j -> first-index wins).
    #pragma unroll
    for (int i = 0; i < 8; ++i) {
        float bv = 0.f; int bi = -1;
        #pragma unroll
        for (int j = 0; j < 8; ++j) {
            int cidx = tx * 8 + j;
            float score = fmaf(-2.0f, acc[i][j], cnS[cidx]);
            if (bi < 0 || score < bv) { bv = score; bi = cidx; }
        }
        red_v[ty * 8 + i][tx] = bv;
        red_i[ty * 8 + i][tx] = bi;
    }
    __syncthreads();

    // 128 threads reduce 16 partials each; ascending t + strict < keeps the
    // first (lowest) code index on ties, matching numpy argmin.
    if (tid < BM) {
        float bv = red_v[tid][0]; int bi = red_i[tid][0];
        #pragma unroll
        for (int t = 1; t < 16; ++t) {
            float v = red_v[tid][t];
            if (v < bv) { bv = v; bi = red_i[tid][t]; }
        }
        amin[tid] = bi;
    }
    __syncthreads();

    // Gather: each wave copies rows (wave, wave+4, ...): 512 floats/row from
    // the (L2-hot) codebook to both q outputs. 8 floats/lane.
    const int wv = tid >> 6, lane = tid & 63;
    for (int r = wv; r < BM; r += 4) {
        int idx = amin[r];
        const float4* src = (const float4*)&cb[(size_t)idx * DIM];
        float4 v0 = src[lane * 2 + 0];
        float4 v1 = src[lane * 2 + 1];
        float4* dst1 = (float4*)&q1[(row0 + r) * DIM];
        float4* dst2 = (float4*)&q2[(row0 + r) * DIM];
        dst1[lane * 2 + 0] = v0; dst1[lane * 2 + 1] = v1;
        dst2[lane * 2 + 0] = v0; dst2[lane * 2 + 1] = v1;
    }
}

// ---------------------------------------------------------------------------
extern "C" void kernel_launch(void* const* d_in, const int* in_sizes, int n_in,
                              void* d_out, int out_size, void* d_ws, size_t ws_size,
                              hipStream_t stream) {
    const float* x    = (const float*)d_in[0];   // [B, DIM], B = 32768
    const float* Wenc = (const float*)d_in[1];   // [DIM, DIM]
    const float* benc = (const float*)d_in[2];   // [DIM]
    const float* cb   = (const float*)d_in[3];   // [NCODES, DIM]

    const int B = in_sizes[0] / DIM;             // 32768

    float* out = (float*)d_out;
    float* q1 = out;                              // q reshaped (same data)
    float* q2 = out + (size_t)B * DIM;            // q
    float* z  = out + (size_t)2 * B * DIM;        // z

    float* cn = (float*)d_ws;                     // 128 floats scratch

    code_norms_kernel<<<1, 128, 0, stream>>>(cb, cn);

    dim3 g1(B / BM, DIM / BM);                    // 256 x 4
    gemm_xwt_kernel<<<g1, 256, 0, stream>>>(x, Wenc, benc, z);

    vq_argmin_gather_kernel<<<B / BM, 256, 0, stream>>>(z, cb, cn, q1, q2);
}

// Round 2
// 338.591 us; speedup vs baseline: 1.5342x; 1.5342x over previous
//
#include <hip/hip_runtime.h>
#include <cstdint>
#include <cstddef>

// x [8,4096,512] fp32, W_enc [512,512], b_enc [512], code_book [128,512].
// Outputs: q, q, z -> 3 x B*DIM fp32. B = 32768.
//
// Strategy: no fp32 MFMA on CDNA4 -> f16 hi/lo split GEMM (3 MFMAs per tile,
// ~22 mantissa bits => z error ~1e-6, argmin-safe) for both the encoder GEMM
// and the code-distance GEMM.

#define DIM     512
#define NCODES  128
#define LDH     40   // padded LDS row stride in halves (80B: bank stride 20 -> 2-way max)

typedef _Float16 half8  __attribute__((ext_vector_type(8)));
typedef _Float16 half4h __attribute__((ext_vector_type(4)));
typedef float    f32x4  __attribute__((ext_vector_type(4)));

__device__ __forceinline__ void split_f32(float v, _Float16& h, _Float16& l) {
    h = (_Float16)v;
    l = (_Float16)(v - (float)h);
}

// ---------------------------------------------------------------------------
// Kernel 0: per-code squared norms. 16 blocks x 256 thr, 32 lanes per code.
// ---------------------------------------------------------------------------
__global__ void code_norms_kernel(const float* __restrict__ cb,
                                  float* __restrict__ cn) {
    const int tid = threadIdx.x;
    const int g = tid >> 5, l = tid & 31;
    const int code = blockIdx.x * 8 + g;
    const float4* row = (const float4*)(cb + (size_t)code * DIM);
    float s = 0.f;
    #pragma unroll
    for (int i = 0; i < 4; ++i) {
        float4 v = row[l + 32 * i];
        s = fmaf(v.x, v.x, s); s = fmaf(v.y, v.y, s);
        s = fmaf(v.z, v.z, s); s = fmaf(v.w, v.w, s);
    }
    #pragma unroll
    for (int m = 16; m >= 1; m >>= 1) s += __shfl_xor(s, m, 64);
    if (l == 0) cn[code] = s;
}

// ---------------------------------------------------------------------------
// Kernel 1: Z = X @ W^T + bias via f16-split MFMA.
// 128x128 C-tile, 256 thr (4 waves), wave owns 64x64 = 4x4 tiles of 16x16.
// A[m][k] frag: lane m=lane&15, k=(lane>>4)*8+j ; B[n][k] same; D: col=lane&15,
// row=(lane>>4)*4+reg  (verified layouts, cdna_hip_programming §3).
// ---------------------------------------------------------------------------
__global__ __launch_bounds__(256) void gemm_mfma_split_kernel(
        const float* __restrict__ X, const float* __restrict__ W,
        const float* __restrict__ bias, float* __restrict__ Z) {
    __shared__ _Float16 Ah[128][LDH];
    __shared__ _Float16 Al[128][LDH];
    __shared__ _Float16 Bh[128][LDH];
    __shared__ _Float16 Bl[128][LDH];
    __shared__ float biasS[128];

    const int tid  = threadIdx.x;
    const int w    = tid >> 6;
    const int lane = tid & 63;
    const int quad = lane >> 4;
    const int l15  = lane & 15;
    const int wr   = (w & 1) * 64;
    const int wc   = (w >> 1) * 64;
    const size_t row0 = (size_t)blockIdx.x * 128;
    const size_t col0 = (size_t)blockIdx.y * 128;

    if (tid < 128) biasS[tid] = bias[col0 + tid];

    f32x4 acc[4][4] = {};

    for (int k0 = 0; k0 < DIM; k0 += 32) {
        // Stage + convert: 128 rows x 32 k for A and B; 1024 float4 slots each.
        #pragma unroll
        for (int i = 0; i < 4; ++i) {
            const int slot = tid + 256 * i;
            const int r  = slot >> 3;
            const int kq = slot & 7;
            float4 va = *(const float4*)&X[(row0 + r) * DIM + k0 + kq * 4];
            _Float16 h0, h1, h2, h3, l0, l1, l2, l3;
            split_f32(va.x, h0, l0); split_f32(va.y, h1, l1);
            split_f32(va.z, h2, l2); split_f32(va.w, h3, l3);
            *(half4h*)&Ah[r][kq * 4] = half4h{h0, h1, h2, h3};
            *(half4h*)&Al[r][kq * 4] = half4h{l0, l1, l2, l3};
            float4 vb = *(const float4*)&W[(col0 + r) * DIM + k0 + kq * 4];
            split_f32(vb.x, h0, l0); split_f32(vb.y, h1, l1);
            split_f32(vb.z, h2, l2); split_f32(vb.w, h3, l3);
            *(half4h*)&Bh[r][kq * 4] = half4h{h0, h1, h2, h3};
            *(half4h*)&Bl[r][kq * 4] = half4h{l0, l1, l2, l3};
        }
        __syncthreads();

        half8 ah[4], al[4], bh[4], bl[4];
        #pragma unroll
        for (int i = 0; i < 4; ++i) {
            ah[i] = *(const half8*)&Ah[wr + i * 16 + l15][quad * 8];
            al[i] = *(const half8*)&Al[wr + i * 16 + l15][quad * 8];
            bh[i] = *(const half8*)&Bh[wc + i * 16 + l15][quad * 8];
            bl[i] = *(const half8*)&Bl[wc + i * 16 + l15][quad * 8];
        }
        #pragma unroll
        for (int i = 0; i < 4; ++i)
            #pragma unroll
            for (int j = 0; j < 4; ++j) {
                acc[i][j] = __builtin_amdgcn_mfma_f32_16x16x32_f16(ah[i], bh[j], acc[i][j], 0, 0, 0);
                acc[i][j] = __builtin_amdgcn_mfma_f32_16x16x32_f16(ah[i], bl[j], acc[i][j], 0, 0, 0);
                acc[i][j] = __builtin_amdgcn_mfma_f32_16x16x32_f16(al[i], bh[j], acc[i][j], 0, 0, 0);
            }
        __syncthreads();
    }

    #pragma unroll
    for (int j = 0; j < 4; ++j) {
        const size_t col = col0 + wc + j * 16 + l15;
        const float bv = biasS[wc + j * 16 + l15];
        #pragma unroll
        for (int i = 0; i < 4; ++i) {
            const size_t rbase = row0 + wr + i * 16 + quad * 4;
            #pragma unroll
            for (int reg = 0; reg < 4; ++reg)
                Z[(rbase + reg) * DIM + col] = acc[i][j][reg] + bv;
        }
    }
}

// ---------------------------------------------------------------------------
// Kernel 2: per 64-row block (512 blocks): S = Z @ CB^T via f16-split MFMA,
// score = cn - 2S, per-row argmin (numpy first-index ties), gather codebook
// row to q1 and q2. Wave w owns rows w*16..w*16+15 x all 128 codes.
// ---------------------------------------------------------------------------
__global__ __launch_bounds__(256) void vq_mfma_kernel(
        const float* __restrict__ Zin, const float* __restrict__ cb,
        const float* __restrict__ cn, float* __restrict__ q1,
        float* __restrict__ q2) {
    __shared__ _Float16 Zh[64][LDH];
    __shared__ _Float16 Zl[64][LDH];
    __shared__ _Float16 Ch[128][LDH];
    __shared__ _Float16 Cl[128][LDH];
    __shared__ float cnS[NCODES];
    __shared__ int amin[64];

    const int tid  = threadIdx.x;
    const int w    = tid >> 6;
    const int lane = tid & 63;
    const int quad = lane >> 4;
    const int l15  = lane & 15;
    const size_t row0 = (size_t)blockIdx.x * 64;

    if (tid < NCODES) cnS[tid] = cn[tid];

    f32x4 acc[8] = {};

    for (int k0 = 0; k0 < DIM; k0 += 32) {
        #pragma unroll
        for (int i = 0; i < 2; ++i) {            // Z: 64 rows x 8 slots = 512
            const int slot = tid + 256 * i;
            const int r  = slot >> 3;
            const int kq = slot & 7;
            float4 v = *(const float4*)&Zin[(row0 + r) * DIM + k0 + kq * 4];
            _Float16 h0, h1, h2, h3, l0, l1, l2, l3;
            split_f32(v.x, h0, l0); split_f32(v.y, h1, l1);
            split_f32(v.z, h2, l2); split_f32(v.w, h3, l3);
            *(half4h*)&Zh[r][kq * 4] = half4h{h0, h1, h2, h3};
            *(half4h*)&Zl[r][kq * 4] = half4h{l0, l1, l2, l3};
        }
        #pragma unroll
        for (int i = 0; i < 4; ++i) {            // CB: 128 rows x 8 slots = 1024
            const int slot = tid + 256 * i;
            const int r  = slot >> 3;
            const int kq = slot & 7;
            float4 v = *(const float4*)&cb[(size_t)r * DIM + k0 + kq * 4];
            _Float16 h0, h1, h2, h3, l0, l1, l2, l3;
            split_f32(v.x, h0, l0); split_f32(v.y, h1, l1);
            split_f32(v.z, h2, l2); split_f32(v.w, h3, l3);
            *(half4h*)&Ch[r][kq * 4] = half4h{h0, h1, h2, h3};
            *(half4h*)&Cl[r][kq * 4] = half4h{l0, l1, l2, l3};
        }
        __syncthreads();

        const half8 zh = *(const half8*)&Zh[w * 16 + l15][quad * 8];
        const half8 zl = *(const half8*)&Zl[w * 16 + l15][quad * 8];
        #pragma unroll
        for (int j = 0; j < 8; ++j) {
            half8 ch = *(const half8*)&Ch[j * 16 + l15][quad * 8];
            half8 cl = *(const half8*)&Cl[j * 16 + l15][quad * 8];
            acc[j] = __builtin_amdgcn_mfma_f32_16x16x32_f16(zh, ch, acc[j], 0, 0, 0);
            acc[j] = __builtin_amdgcn_mfma_f32_16x16x32_f16(zh, cl, acc[j], 0, 0, 0);
            acc[j] = __builtin_amdgcn_mfma_f32_16x16x32_f16(zl, ch, acc[j], 0, 0, 0);
        }
        __syncthreads();
    }

    // Row argmin. Lane holds rows quad*4+reg (of wave's 16-row group), col
    // j*16+l15. Ascending j + strict < keeps smallest col per lane; cross-lane
    // butterfly over the 16 lanes of the quad keeps smallest index on ties.
    #pragma unroll
    for (int reg = 0; reg < 4; ++reg) {
        float bv = fmaf(-2.f, acc[0][reg], cnS[l15]);
        int bi = l15;
        #pragma unroll
        for (int j = 1; j < 8; ++j) {
            const int c = j * 16 + l15;
            const float s = fmaf(-2.f, acc[j][reg], cnS[c]);
            if (s < bv) { bv = s; bi = c; }
        }
        #pragma unroll
        for (int m = 1; m <= 8; m <<= 1) {
            const float ov = __shfl_xor(bv, m, 64);
            const int   oi = __shfl_xor(bi, m, 64);
            if (ov < bv || (ov == bv && oi < bi)) { bv = ov; bi = oi; }
        }
        if (l15 == 0) amin[w * 16 + quad * 4 + reg] = bi;
    }
    __syncthreads();

    // Gather: wave per row (rows w, w+4, ...), 8 floats/lane, bitwise codebook.
    for (int r = w; r < 64; r += 4) {
        const int idx = amin[r];
        const float4* src = (const float4*)&cb[(size_t)idx * DIM];
        float4 v0 = src[lane * 2 + 0];
        float4 v1 = src[lane * 2 + 1];
        float4* d1 = (float4*)&q1[(row0 + r) * DIM];
        float4* d2 = (float4*)&q2[(row0 + r) * DIM];
        d1[lane * 2 + 0] = v0; d1[lane * 2 + 1] = v1;
        d2[lane * 2 + 0] = v0; d2[lane * 2 + 1] = v1;
    }
}

// ---------------------------------------------------------------------------
extern "C" void kernel_launch(void* const* d_in, const int* in_sizes, int n_in,
                              void* d_out, int out_size, void* d_ws, size_t ws_size,
                              hipStream_t stream) {
    const float* x    = (const float*)d_in[0];
    const float* Wenc = (const float*)d_in[1];
    const float* benc = (const float*)d_in[2];
    const float* cb   = (const float*)d_in[3];

    const int B = in_sizes[0] / DIM;             // 32768

    float* out = (float*)d_out;
    float* q1 = out;
    float* q2 = out + (size_t)B * DIM;
    float* z  = out + (size_t)2 * B * DIM;

    float* cn = (float*)d_ws;

    code_norms_kernel<<<NCODES / 8, 256, 0, stream>>>(cb, cn);

    dim3 g1(B / 128, DIM / 128);                 // 256 x 4
    gemm_mfma_split_kernel<<<g1, 256, 0, stream>>>(x, Wenc, benc, z);

    vq_mfma_kernel<<<B / 64, 256, 0, stream>>>(z, cb, cn, q1, q2);
}

// Round 3
// 314.863 us; speedup vs baseline: 1.6498x; 1.0754x over previous
//
#include <hip/hip_runtime.h>
#include <cstdint>
#include <cstddef>

// x [8,4096,512] fp32, W_enc [512,512], b_enc [512], code_book [128,512].
// Outputs: q, q, z -> 3 x B*DIM fp32. B = 32768.
//
// f16 hi/lo split MFMA (3 products, ~22 mantissa bits) for both GEMMs.
// W/cb pre-split once to ws; x/z staged raw f32 via global_load_lds and
// split in-register at fragment-load time. XOR-swizzled LDS (no padding —
// global_load_lds needs lane-contiguous layout) makes b128 frag reads
// bank-uniform.

#define DIM     512
#define NCODES  128

typedef _Float16 half8  __attribute__((ext_vector_type(8)));
typedef _Float16 half4h __attribute__((ext_vector_type(4)));
typedef float    f32x4  __attribute__((ext_vector_type(4)));

__device__ __forceinline__ void load_lds16(const void* gptr, void* ldsptr) {
    __builtin_amdgcn_global_load_lds(
        (const __attribute__((address_space(1))) uint32_t*)(uintptr_t)gptr,
        (__attribute__((address_space(3))) uint32_t*)(uintptr_t)ldsptr,
        16, 0, 0);
}

__device__ __forceinline__ void split_f32(float v, _Float16& h, _Float16& l) {
    h = (_Float16)v;
    l = (_Float16)(v - (float)h);
}

// ---------------------------------------------------------------------------
// Kernel P: split W (512x512) and cb (128x512) into f16 hi/lo arrays in ws.
// 320 blocks x 256 thr x 1 float4 each = 327680 floats total.
// ---------------------------------------------------------------------------
__global__ __launch_bounds__(256) void presplit_kernel(
        const float* __restrict__ W, const float* __restrict__ cb,
        _Float16* __restrict__ Wh, _Float16* __restrict__ Wl,
        _Float16* __restrict__ Ch, _Float16* __restrict__ Cl) {
    const int gid = blockIdx.x * 256 + threadIdx.x;
    const float* src; _Float16 *dh, *dl; size_t e;
    if (gid < 65536) { src = W;  dh = Wh; dl = Wl; e = (size_t)gid * 4; }
    else             { src = cb; dh = Ch; dl = Cl; e = (size_t)(gid - 65536) * 4; }
    float4 v = *(const float4*)&src[e];
    _Float16 h0, h1, h2, h3, l0, l1, l2, l3;
    split_f32(v.x, h0, l0); split_f32(v.y, h1, l1);
    split_f32(v.z, h2, l2); split_f32(v.w, h3, l3);
    *(half4h*)&dh[e] = half4h{h0, h1, h2, h3};
    *(half4h*)&dl[e] = half4h{l0, l1, l2, l3};
}

// ---------------------------------------------------------------------------
// Kernel 0: per-code squared norms (fp32). 16 blocks x 256 thr.
// ---------------------------------------------------------------------------
__global__ void code_norms_kernel(const float* __restrict__ cb,
                                  float* __restrict__ cn) {
    const int tid = threadIdx.x;
    const int g = tid >> 5, l = tid & 31;
    const int code = blockIdx.x * 8 + g;
    const float4* row = (const float4*)(cb + (size_t)code * DIM);
    float s = 0.f;
    #pragma unroll
    for (int i = 0; i < 4; ++i) {
        float4 v = row[l + 32 * i];
        s = fmaf(v.x, v.x, s); s = fmaf(v.y, v.y, s);
        s = fmaf(v.z, v.z, s); s = fmaf(v.w, v.w, s);
    }
    #pragma unroll
    for (int m = 16; m >= 1; m >>= 1) s += __shfl_xor(s, m, 64);
    if (l == 0) cn[code] = s;
}

// ---------------------------------------------------------------------------
// Kernel G: Z = X @ W^T + bias. 128x128 tile, BK=32, 256 thr (4 waves),
// wave owns 64x64. X staged f32 (split at frag load); W staged pre-split.
// LDS swizzle: Xs 16B-chunk p of row r holds global chunk p^(r&7);
//              BhS/BlS chunk p of row r holds global chunk p^((r>>1)&3).
// ---------------------------------------------------------------------------
__global__ __launch_bounds__(256) void gemm_kernel(
        const float* __restrict__ X, const _Float16* __restrict__ Wh,
        const _Float16* __restrict__ Wl, const float* __restrict__ bias,
        float* __restrict__ Z) {
    __shared__ float    Xs[128][32];     // 16 KB
    __shared__ _Float16 BhS[128][32];    // 8 KB
    __shared__ _Float16 BlS[128][32];    // 8 KB
    __shared__ float    biasS[128];

    const int tid  = threadIdx.x;
    const int lane = tid & 63;
    const int w    = tid >> 6;
    const int quad = lane >> 4;
    const int l15  = lane & 15;
    const int wr   = (w & 1) * 64;
    const int wc   = (w >> 1) * 64;
    const size_t row0 = (size_t)blockIdx.x * 128;
    const size_t col0 = (size_t)blockIdx.y * 128;
    const int wbase = tid & 192;         // wave-uniform thread base

    if (tid < 128) biasS[tid] = bias[col0 + tid];

    f32x4 acc[4][4] = {};

    for (int k0 = 0; k0 < DIM; k0 += 32) {
        // X: 1024 chunks of 16B, 4 per thread.
        #pragma unroll
        for (int i = 0; i < 4; ++i) {
            const int slot = i * 256 + tid;
            const int r = slot >> 3, p = slot & 7;
            const int g = p ^ (r & 7);
            load_lds16(&X[(row0 + r) * DIM + k0 + g * 4],
                       (char*)&Xs[0][0] + (size_t)(i * 256 + wbase) * 16);
        }
        // Wh/Wl: 512 chunks each, 2 per thread each.
        #pragma unroll
        for (int i = 0; i < 2; ++i) {
            const int slot = i * 256 + tid;
            const int r = slot >> 2, p = slot & 3;
            const int g = p ^ ((r >> 1) & 3);
            load_lds16(&Wh[(col0 + r) * DIM + k0 + g * 8],
                       (char*)&BhS[0][0] + (size_t)(i * 256 + wbase) * 16);
            load_lds16(&Wl[(col0 + r) * DIM + k0 + g * 8],
                       (char*)&BlS[0][0] + (size_t)(i * 256 + wbase) * 16);
        }
        __syncthreads();   // drains vmcnt (global_load_lds) per barrier semantics

        half8 ah[4], al[4], bh[4], bl[4];
        #pragma unroll
        for (int i = 0; i < 4; ++i) {
            const int row = wr + i * 16 + l15;
            const int p0 = (2 * quad)     ^ (row & 7);
            const int p1 = (2 * quad + 1) ^ (row & 7);
            f32x4 va = *(const f32x4*)&Xs[row][p0 * 4];
            f32x4 vb = *(const f32x4*)&Xs[row][p1 * 4];
            _Float16 h[8], l[8];
            split_f32(va[0], h[0], l[0]); split_f32(va[1], h[1], l[1]);
            split_f32(va[2], h[2], l[2]); split_f32(va[3], h[3], l[3]);
            split_f32(vb[0], h[4], l[4]); split_f32(vb[1], h[5], l[5]);
            split_f32(vb[2], h[6], l[6]); split_f32(vb[3], h[7], l[7]);
            ah[i] = half8{h[0], h[1], h[2], h[3], h[4], h[5], h[6], h[7]};
            al[i] = half8{l[0], l[1], l[2], l[3], l[4], l[5], l[6], l[7]};
        }
        #pragma unroll
        for (int j = 0; j < 4; ++j) {
            const int row = wc + j * 16 + l15;
            const int p = quad ^ ((row >> 1) & 3);
            bh[j] = *(const half8*)&BhS[row][p * 8];
            bl[j] = *(const half8*)&BlS[row][p * 8];
        }
        #pragma unroll
        for (int i = 0; i < 4; ++i)
            #pragma unroll
            for (int j = 0; j < 4; ++j) {
                acc[i][j] = __builtin_amdgcn_mfma_f32_16x16x32_f16(ah[i], bh[j], acc[i][j], 0, 0, 0);
                acc[i][j] = __builtin_amdgcn_mfma_f32_16x16x32_f16(ah[i], bl[j], acc[i][j], 0, 0, 0);
                acc[i][j] = __builtin_amdgcn_mfma_f32_16x16x32_f16(al[i], bh[j], acc[i][j], 0, 0, 0);
            }
        __syncthreads();
    }

    // Epilogue: + bias; D layout col=lane&15, row=quad*4+reg.
    #pragma unroll
    for (int j = 0; j < 4; ++j) {
        const int ccol = wc + j * 16 + l15;
        const float bv = biasS[ccol];
        #pragma unroll
        for (int i = 0; i < 4; ++i) {
            const size_t rbase = row0 + wr + i * 16 + quad * 4;
            #pragma unroll
            for (int reg = 0; reg < 4; ++reg)
                Z[(rbase + reg) * DIM + col0 + ccol] = acc[i][j][reg] + bv;
        }
    }
}

// ---------------------------------------------------------------------------
// Kernel V: per 64-row block (512 blocks): S = Z @ CB^T (f16-split MFMA),
// score = cn - 2S, row argmin (numpy first-index ties), gather cb row.
// Z staged f32 + in-register split; cb staged from pre-split Ch/Cl.
// ---------------------------------------------------------------------------
__global__ __launch_bounds__(256) void vq_kernel(
        const float* __restrict__ Zin, const _Float16* __restrict__ Ch,
        const _Float16* __restrict__ Cl, const float* __restrict__ cb,
        const float* __restrict__ cn, float* __restrict__ q1,
        float* __restrict__ q2) {
    __shared__ float    Zs[64][32];      // 8 KB
    __shared__ _Float16 ChS[128][32];    // 8 KB
    __shared__ _Float16 ClS[128][32];    // 8 KB
    __shared__ float cnS[NCODES];
    __shared__ int   amin[64];

    const int tid  = threadIdx.x;
    const int lane = tid & 63;
    const int w    = tid >> 6;
    const int quad = lane >> 4;
    const int l15  = lane & 15;
    const size_t row0 = (size_t)blockIdx.x * 64;
    const int wbase = tid & 192;

    if (tid < NCODES) cnS[tid] = cn[tid];

    f32x4 acc[8] = {};

    for (int k0 = 0; k0 < DIM; k0 += 32) {
        #pragma unroll
        for (int i = 0; i < 2; ++i) {     // Z: 512 chunks, 2/thread
            const int slot = i * 256 + tid;
            const int r = slot >> 3, p = slot & 7;
            const int g = p ^ (r & 7);
            load_lds16(&Zin[(row0 + r) * DIM + k0 + g * 4],
                       (char*)&Zs[0][0] + (size_t)(i * 256 + wbase) * 16);
        }
        #pragma unroll
        for (int i = 0; i < 2; ++i) {     // Ch/Cl: 512 chunks each, 2/thread
            const int slot = i * 256 + tid;
            const int r = slot >> 2, p = slot & 3;
            const int g = p ^ ((r >> 1) & 3);
            load_lds16(&Ch[(size_t)r * DIM + k0 + g * 8],
                       (char*)&ChS[0][0] + (size_t)(i * 256 + wbase) * 16);
            load_lds16(&Cl[(size_t)r * DIM + k0 + g * 8],
                       (char*)&ClS[0][0] + (size_t)(i * 256 + wbase) * 16);
        }
        __syncthreads();

        const int zrow = w * 16 + l15;
        const int p0 = (2 * quad)     ^ (zrow & 7);
        const int p1 = (2 * quad + 1) ^ (zrow & 7);
        f32x4 va = *(const f32x4*)&Zs[zrow][p0 * 4];
        f32x4 vb = *(const f32x4*)&Zs[zrow][p1 * 4];
        _Float16 h[8], l[8];
        split_f32(va[0], h[0], l[0]); split_f32(va[1], h[1], l[1]);
        split_f32(va[2], h[2], l[2]); split_f32(va[3], h[3], l[3]);
        split_f32(vb[0], h[4], l[4]); split_f32(vb[1], h[5], l[5]);
        split_f32(vb[2], h[6], l[6]); split_f32(vb[3], h[7], l[7]);
        const half8 zh = half8{h[0], h[1], h[2], h[3], h[4], h[5], h[6], h[7]};
        const half8 zl = half8{l[0], l[1], l[2], l[3], l[4], l[5], l[6], l[7]};

        #pragma unroll
        for (int j = 0; j < 8; ++j) {
            const int crow = j * 16 + l15;
            const int p = quad ^ ((crow >> 1) & 3);
            half8 ch = *(const half8*)&ChS[crow][p * 8];
            half8 cl = *(const half8*)&ClS[crow][p * 8];
            acc[j] = __builtin_amdgcn_mfma_f32_16x16x32_f16(zh, ch, acc[j], 0, 0, 0);
            acc[j] = __builtin_amdgcn_mfma_f32_16x16x32_f16(zh, cl, acc[j], 0, 0, 0);
            acc[j] = __builtin_amdgcn_mfma_f32_16x16x32_f16(zl, ch, acc[j], 0, 0, 0);
        }
        __syncthreads();
    }

    // Row argmin: lane holds row quad*4+reg of wave's 16-row group, col j*16+l15.
    #pragma unroll
    for (int reg = 0; reg < 4; ++reg) {
        float bv = fmaf(-2.f, acc[0][reg], cnS[l15]);
        int bi = l15;
        #pragma unroll
        for (int j = 1; j < 8; ++j) {
            const int c = j * 16 + l15;
            const float s = fmaf(-2.f, acc[j][reg], cnS[c]);
            if (s < bv) { bv = s; bi = c; }
        }
        #pragma unroll
        for (int m = 1; m <= 8; m <<= 1) {
            const float ov = __shfl_xor(bv, m, 64);
            const int   oi = __shfl_xor(bi, m, 64);
            if (ov < bv || (ov == bv && oi < bi)) { bv = ov; bi = oi; }
        }
        if (l15 == 0) amin[w * 16 + quad * 4 + reg] = bi;
    }
    __syncthreads();

    // Gather: wave per row, 8 floats/lane, bitwise codebook copy to q1,q2.
    for (int r = w; r < 64; r += 4) {
        const int idx = amin[r];
        const float4* src = (const float4*)&cb[(size_t)idx * DIM];
        float4 v0 = src[lane * 2 + 0];
        float4 v1 = src[lane * 2 + 1];
        float4* d1 = (float4*)&q1[(row0 + r) * DIM];
        float4* d2 = (float4*)&q2[(row0 + r) * DIM];
        d1[lane * 2 + 0] = v0; d1[lane * 2 + 1] = v1;
        d2[lane * 2 + 0] = v0; d2[lane * 2 + 1] = v1;
    }
}

// ---------------------------------------------------------------------------
extern "C" void kernel_launch(void* const* d_in, const int* in_sizes, int n_in,
                              void* d_out, int out_size, void* d_ws, size_t ws_size,
                              hipStream_t stream) {
    const float* x    = (const float*)d_in[0];
    const float* Wenc = (const float*)d_in[1];
    const float* benc = (const float*)d_in[2];
    const float* cb   = (const float*)d_in[3];

    const int B = in_sizes[0] / DIM;             // 32768

    float* out = (float*)d_out;
    float* q1 = out;
    float* q2 = out + (size_t)B * DIM;
    float* z  = out + (size_t)2 * B * DIM;

    // ws carve (16B-aligned): cn | Wh | Wl | Ch | Cl  (~1.3 MB total)
    char* wsb = (char*)d_ws;
    float*    cn = (float*)wsb;                          // 512 B
    _Float16* Wh = (_Float16*)(wsb + 4096);              // 512 KB
    _Float16* Wl = (_Float16*)(wsb + 4096 + 524288);     // 512 KB
    _Float16* Ch = (_Float16*)(wsb + 4096 + 1048576);    // 128 KB
    _Float16* Cl = (_Float16*)(wsb + 4096 + 1179648);    // 128 KB

    presplit_kernel<<<320, 256, 0, stream>>>(Wenc, cb, Wh, Wl, Ch, Cl);
    code_norms_kernel<<<NCODES / 8, 256, 0, stream>>>(cb, cn);

    dim3 g1(B / 128, DIM / 128);                 // 256 x 4
    gemm_kernel<<<g1, 256, 0, stream>>>(x, Wh, Wl, benc, z);

    vq_kernel<<<B / 64, 256, 0, stream>>>(z, Ch, Cl, cb, cn, q1, q2);
}

// Round 4
// 309.002 us; speedup vs baseline: 1.6811x; 1.0190x over previous
//
#include <hip/hip_runtime.h>
#include <cstdint>
#include <cstddef>

// x [8,4096,512] fp32, W_enc [512,512], b_enc [512], code_book [128,512].
// Outputs: q, q, z -> 3 x B*DIM fp32. B = 32768.
//
// Fused design: one kernel does z = x@W^T+b (f16 hi/lo split MFMA, 3
// products, ~22 mantissa bits), then S = z@cb^T from the in-register z
// (LDS transpose round-trip D-layout -> A-layout), argmin, gather.
// z is written to HBM once and never re-read. W/cb pre-split once to ws.

#define DIM     512
#define NCODES  128

typedef _Float16 half8  __attribute__((ext_vector_type(8)));
typedef _Float16 half4h __attribute__((ext_vector_type(4)));
typedef float    f32x4  __attribute__((ext_vector_type(4)));

__device__ __forceinline__ void load_lds16(const void* gptr, void* ldsptr) {
    __builtin_amdgcn_global_load_lds(
        (const __attribute__((address_space(1))) uint32_t*)(uintptr_t)gptr,
        (__attribute__((address_space(3))) uint32_t*)(uintptr_t)ldsptr,
        16, 0, 0);
}

__device__ __forceinline__ void split_f32(float v, _Float16& h, _Float16& l) {
    h = (_Float16)v;
    l = (_Float16)(v - (float)h);
}

// ---------------------------------------------------------------------------
// Kernel P: split W (512x512) and cb (128x512) into f16 hi/lo arrays in ws.
// ---------------------------------------------------------------------------
__global__ __launch_bounds__(256) void presplit_kernel(
        const float* __restrict__ W, const float* __restrict__ cb,
        _Float16* __restrict__ Wh, _Float16* __restrict__ Wl,
        _Float16* __restrict__ Ch, _Float16* __restrict__ Cl) {
    const int gid = blockIdx.x * 256 + threadIdx.x;
    const float* src; _Float16 *dh, *dl; size_t e;
    if (gid < 65536) { src = W;  dh = Wh; dl = Wl; e = (size_t)gid * 4; }
    else             { src = cb; dh = Ch; dl = Cl; e = (size_t)(gid - 65536) * 4; }
    float4 v = *(const float4*)&src[e];
    _Float16 h0, h1, h2, h3, l0, l1, l2, l3;
    split_f32(v.x, h0, l0); split_f32(v.y, h1, l1);
    split_f32(v.z, h2, l2); split_f32(v.w, h3, l3);
    *(half4h*)&dh[e] = half4h{h0, h1, h2, h3};
    *(half4h*)&dl[e] = half4h{l0, l1, l2, l3};
}

// ---------------------------------------------------------------------------
// Kernel 0: per-code squared norms (fp32). 16 blocks x 256 thr.
// ---------------------------------------------------------------------------
__global__ void code_norms_kernel(const float* __restrict__ cb,
                                  float* __restrict__ cn) {
    const int tid = threadIdx.x;
    const int g = tid >> 5, l = tid & 31;
    const int code = blockIdx.x * 8 + g;
    const float4* row = (const float4*)(cb + (size_t)code * DIM);
    float s = 0.f;
    #pragma unroll
    for (int i = 0; i < 4; ++i) {
        float4 v = row[l + 32 * i];
        s = fmaf(v.x, v.x, s); s = fmaf(v.y, v.y, s);
        s = fmaf(v.z, v.z, s); s = fmaf(v.w, v.w, s);
    }
    #pragma unroll
    for (int m = 16; m >= 1; m >>= 1) s += __shfl_xor(s, m, 64);
    if (l == 0) cn[code] = s;
}

// ---------------------------------------------------------------------------
// Fused kernel: 512 blocks x 64 rows, 256 thr (4 waves), wave owns 16 rows.
// For nc chunk (128 z-cols): z-chunk = X@W^T (K=512), +bias -> global z and
// split -> zhS/zlS (A-layout); then S += z_chunk @ cb_chunk^T (K=128).
// Finally: row argmin over 128 codes, gather codebook row to q1,q2.
// LDS swizzles (round-3 proven): Xs 16B-chunk p of row r holds global chunk
// p^(r&7); BhS/BlS chunk p of row r holds global chunk p^((r>>1)&3).
// ---------------------------------------------------------------------------
__global__ __launch_bounds__(256, 2) void fused_kernel(
        const float* __restrict__ X, const _Float16* __restrict__ Wh,
        const _Float16* __restrict__ Wl, const _Float16* __restrict__ Ch,
        const _Float16* __restrict__ Cl, const float* __restrict__ cb,
        const float* __restrict__ bias, const float* __restrict__ cn,
        float* __restrict__ Z, float* __restrict__ q1,
        float* __restrict__ q2) {
    __shared__ float    Xs[64][32];       // 8 KB
    __shared__ _Float16 BhS[128][32];     // 8 KB (W tile, reused for cb)
    __shared__ _Float16 BlS[128][32];     // 8 KB
    __shared__ _Float16 zhS[64][132];     // 16.5 KB (stride 132: conflict-free)
    __shared__ _Float16 zlS[64][132];     // 16.5 KB
    __shared__ float    biasS[DIM];       // 2 KB
    __shared__ float    cnS[NCODES];
    __shared__ int      amin[64];

    const int tid  = threadIdx.x;
    const int lane = tid & 63;
    const int w    = tid >> 6;
    const int quad = lane >> 4;
    const int l15  = lane & 15;
    const int rw   = w * 16;              // wave's row base (local)
    const size_t row0 = (size_t)blockIdx.x * 64;
    const int wbase = tid & 192;          // wave-uniform thread base

    biasS[tid] = bias[tid];
    biasS[tid + 256] = bias[tid + 256];
    if (tid < NCODES) cnS[tid] = cn[tid];

    f32x4 Sacc[8] = {};

    for (int nc = 0; nc < 4; ++nc) {
        const int col0 = nc * 128;
        f32x4 zacc[8] = {};

        for (int k0 = 0; k0 < DIM; k0 += 32) {
            // X: 512 chunks of 16B (4 floats), 2/thread.
            #pragma unroll
            for (int i = 0; i < 2; ++i) {
                const int slot = i * 256 + tid;
                const int r = slot >> 3, p = slot & 7;
                const int g = p ^ (r & 7);
                load_lds16(&X[(row0 + r) * DIM + k0 + g * 4],
                           (char*)&Xs[0][0] + (size_t)(i * 256 + wbase) * 16);
            }
            // W rows col0..col0+127: 512 chunks (8 halves) each h/l, 2/thread.
            #pragma unroll
            for (int i = 0; i < 2; ++i) {
                const int slot = i * 256 + tid;
                const int r = slot >> 2, p = slot & 3;
                const int g = p ^ ((r >> 1) & 3);
                load_lds16(&Wh[(size_t)(col0 + r) * DIM + k0 + g * 8],
                           (char*)&BhS[0][0] + (size_t)(i * 256 + wbase) * 16);
                load_lds16(&Wl[(size_t)(col0 + r) * DIM + k0 + g * 8],
                           (char*)&BlS[0][0] + (size_t)(i * 256 + wbase) * 16);
            }
            __syncthreads();

            // A frags: X rows rw..rw+15, split in-register.
            const int xrow = rw + l15;
            const int p0 = (2 * quad)     ^ (xrow & 7);
            const int p1 = (2 * quad + 1) ^ (xrow & 7);
            f32x4 va = *(const f32x4*)&Xs[xrow][p0 * 4];
            f32x4 vb = *(const f32x4*)&Xs[xrow][p1 * 4];
            _Float16 h[8], l[8];
            split_f32(va[0], h[0], l[0]); split_f32(va[1], h[1], l[1]);
            split_f32(va[2], h[2], l[2]); split_f32(va[3], h[3], l[3]);
            split_f32(vb[0], h[4], l[4]); split_f32(vb[1], h[5], l[5]);
            split_f32(vb[2], h[6], l[6]); split_f32(vb[3], h[7], l[7]);
            const half8 ah = half8{h[0], h[1], h[2], h[3], h[4], h[5], h[6], h[7]};
            const half8 al = half8{l[0], l[1], l[2], l[3], l[4], l[5], l[6], l[7]};

            #pragma unroll
            for (int j = 0; j < 8; ++j) {
                const int wrow = j * 16 + l15;
                const int p = quad ^ ((wrow >> 1) & 3);
                half8 bh = *(const half8*)&BhS[wrow][p * 8];
                half8 bl = *(const half8*)&BlS[wrow][p * 8];
                zacc[j] = __builtin_amdgcn_mfma_f32_16x16x32_f16(ah, bh, zacc[j], 0, 0, 0);
                zacc[j] = __builtin_amdgcn_mfma_f32_16x16x32_f16(ah, bl, zacc[j], 0, 0, 0);
                zacc[j] = __builtin_amdgcn_mfma_f32_16x16x32_f16(al, bh, zacc[j], 0, 0, 0);
            }
            __syncthreads();
        }

        // Epilogue: +bias, store z to global, split into zhS/zlS (A-layout).
        // D layout: row = rw + quad*4 + reg, col (within chunk) = j*16 + l15.
        #pragma unroll
        for (int j = 0; j < 8; ++j) {
            const int ccol = j * 16 + l15;
            const float bv = biasS[col0 + ccol];
            #pragma unroll
            for (int reg = 0; reg < 4; ++reg) {
                const int zrow = rw + quad * 4 + reg;
                const float v = zacc[j][reg] + bv;
                Z[(row0 + zrow) * DIM + col0 + ccol] = v;
                _Float16 hh, ll; split_f32(v, hh, ll);
                zhS[zrow][ccol] = hh;
                zlS[zrow][ccol] = ll;
            }
        }

        // S phase: S += z_chunk @ cb_chunk^T over this 128-d chunk.
        for (int ks = 0; ks < 4; ++ks) {
            #pragma unroll
            for (int i = 0; i < 2; ++i) {
                const int slot = i * 256 + tid;
                const int r = slot >> 2, p = slot & 3;
                const int g = p ^ ((r >> 1) & 3);
                load_lds16(&Ch[(size_t)r * DIM + col0 + ks * 32 + g * 8],
                           (char*)&BhS[0][0] + (size_t)(i * 256 + wbase) * 16);
                load_lds16(&Cl[(size_t)r * DIM + col0 + ks * 32 + g * 8],
                           (char*)&BlS[0][0] + (size_t)(i * 256 + wbase) * 16);
            }
            __syncthreads();   // also covers zhS/zlS writes for ks==0

            const half8 zh = *(const half8*)&zhS[rw + l15][ks * 32 + quad * 8];
            const half8 zl = *(const half8*)&zlS[rw + l15][ks * 32 + quad * 8];
            #pragma unroll
            for (int j = 0; j < 8; ++j) {
                const int crow = j * 16 + l15;
                const int p = quad ^ ((crow >> 1) & 3);
                half8 ch = *(const half8*)&BhS[crow][p * 8];
                half8 cl = *(const half8*)&BlS[crow][p * 8];
                Sacc[j] = __builtin_amdgcn_mfma_f32_16x16x32_f16(zh, ch, Sacc[j], 0, 0, 0);
                Sacc[j] = __builtin_amdgcn_mfma_f32_16x16x32_f16(zh, cl, Sacc[j], 0, 0, 0);
                Sacc[j] = __builtin_amdgcn_mfma_f32_16x16x32_f16(zl, ch, Sacc[j], 0, 0, 0);
            }
            __syncthreads();
        }
    }

    // Row argmin: lane holds S row rw+quad*4+reg, code j*16+l15.
    #pragma unroll
    for (int reg = 0; reg < 4; ++reg) {
        float bv = fmaf(-2.f, Sacc[0][reg], cnS[l15]);
        int bi = l15;
        #pragma unroll
        for (int j = 1; j < 8; ++j) {
            const int c = j * 16 + l15;
            const float s = fmaf(-2.f, Sacc[j][reg], cnS[c]);
            if (s < bv) { bv = s; bi = c; }
        }
        #pragma unroll
        for (int m = 1; m <= 8; m <<= 1) {
            const float ov = __shfl_xor(bv, m, 64);
            const int   oi = __shfl_xor(bi, m, 64);
            if (ov < bv || (ov == bv && oi < bi)) { bv = ov; bi = oi; }
        }
        if (l15 == 0) amin[rw + quad * 4 + reg] = bi;
    }
    __syncthreads();

    // Gather: wave per row, 8 floats/lane, bitwise codebook copy to q1,q2.
    for (int r = w; r < 64; r += 4) {
        const int idx = amin[r];
        const float4* src = (const float4*)&cb[(size_t)idx * DIM];
        float4 v0 = src[lane * 2 + 0];
        float4 v1 = src[lane * 2 + 1];
        float4* d1 = (float4*)&q1[(row0 + r) * DIM];
        float4* d2 = (float4*)&q2[(row0 + r) * DIM];
        d1[lane * 2 + 0] = v0; d1[lane * 2 + 1] = v1;
        d2[lane * 2 + 0] = v0; d2[lane * 2 + 1] = v1;
    }
}

// ---------------------------------------------------------------------------
extern "C" void kernel_launch(void* const* d_in, const int* in_sizes, int n_in,
                              void* d_out, int out_size, void* d_ws, size_t ws_size,
                              hipStream_t stream) {
    const float* x    = (const float*)d_in[0];
    const float* Wenc = (const float*)d_in[1];
    const float* benc = (const float*)d_in[2];
    const float* cb   = (const float*)d_in[3];

    const int B = in_sizes[0] / DIM;             // 32768

    float* out = (float*)d_out;
    float* q1 = out;
    float* q2 = out + (size_t)B * DIM;
    float* z  = out + (size_t)2 * B * DIM;

    // ws carve (16B-aligned): cn | Wh | Wl | Ch | Cl  (~1.3 MB total)
    char* wsb = (char*)d_ws;
    float*    cn = (float*)wsb;                          // 512 B
    _Float16* Wh = (_Float16*)(wsb + 4096);              // 512 KB
    _Float16* Wl = (_Float16*)(wsb + 4096 + 524288);     // 512 KB
    _Float16* Ch = (_Float16*)(wsb + 4096 + 1048576);    // 128 KB
    _Float16* Cl = (_Float16*)(wsb + 4096 + 1179648);    // 128 KB

    presplit_kernel<<<320, 256, 0, stream>>>(Wenc, cb, Wh, Wl, Ch, Cl);
    code_norms_kernel<<<NCODES / 8, 256, 0, stream>>>(cb, cn);

    fused_kernel<<<B / 64, 256, 0, stream>>>(x, Wh, Wl, Ch, Cl, cb, benc, cn,
                                             z, q1, q2);
}